// Round 5
// baseline (240.973 us; speedup 1.0000x reference)
//
#include <hip/hip_runtime.h>

// SMap3x3: per-pixel argmin over 9 key_query planes -> one-hot scatter of
// (x,y,z,r) into a [B,3,3,4,H,W] output. HBM write-bound (177 MB write,
// 64 MB read; floor ~40 us at fill-rate 6.5 TB/s).
//
// Case analysis of the reference (valid/bad mutually exclusive):
//   r<=0.5          : sw = -1 (no xz write), s2 = 4 (center)
//   r>0.5 && z>0    : sw = argmin,           s2 = argmin
//   r>0.5 && z<=0   : sw = 4,                s2 = 4
// out[b,k,c,hw] = c<3 ? ((k==sw) ? {x,y,z}[c] : 0) : ((k==s2) ? r : 0)
//
// R4 lesson: single-pass kernel interleaves 41 address streams per block and
// mixes reads/writes -> well below fill-rate. This version splits:
//   pass 1: selectors -> 1 B/pixel in d_ws (reads z,r,kq = 54 MB)
//   pass 2: one contiguous linear NT-write run per block, per output plane;
//           value planes (19.6 MB) L3-resident across their 9 re-reads.

constexpr int H = 480;
constexpr int W = 640;
constexpr int HW = H * W;          // 307200
constexpr int HW4 = HW / 4;        // 76800 float4 per plane
constexpr int B = 4;
constexpr int BLK = 256;
constexpr int GRIDX1 = HW4 / BLK;  // 300 (exact)
constexpr int S2 = 50;             // chunks per plane in pass 2
constexpr int CHUNK4 = HW4 / S2;   // 1536 float4 per block
constexpr int ITERS2 = CHUNK4 / BLK; // 6

typedef __attribute__((ext_vector_type(4))) float fvec4;

__device__ __forceinline__ fvec4 nt_load4(const fvec4* p) {
    return __builtin_nontemporal_load(p);
}
__device__ __forceinline__ void nt_store4(fvec4* p, fvec4 v) {
    __builtin_nontemporal_store(v, p);
}

// ---------------- Pass 1: per-pixel selector bytes ----------------
// byte = ((sw+1) << 4) | s2 ; sw in [-1,8] -> hi nibble in [0,9]; s2 in [0,8]
__global__ __launch_bounds__(256) void smap_sel_kernel(
    const fvec4* __restrict__ z,
    const fvec4* __restrict__ r,
    const fvec4* __restrict__ kq,
    unsigned int* __restrict__ sel)   // B*HW4 packed uchar4
{
    const int hw4 = blockIdx.x * BLK + threadIdx.x;  // [0, HW4)
    const int b   = blockIdx.y;                      // [0, B)
    const size_t pix = (size_t)b * HW4 + hw4;

    const fvec4 zv = z[pix];          // regular: reused by pass 2 via L3
    const fvec4 rv = r[pix];

    const fvec4* kqb = kq + (size_t)b * 9 * HW4 + hw4;
    fvec4 best = nt_load4(kqb);       // read-once: NT
    int i0 = 0, i1 = 0, i2 = 0, i3 = 0;
#pragma unroll
    for (int k = 1; k < 9; ++k) {
        const fvec4 kk = nt_load4(kqb + (size_t)k * HW4);
        if (kk.x < best.x) { best.x = kk.x; i0 = k; }
        if (kk.y < best.y) { best.y = kk.y; i1 = k; }
        if (kk.z < best.z) { best.z = kk.z; i2 = k; }
        if (kk.w < best.w) { best.w = kk.w; i3 = k; }
    }

    unsigned int b0, b1, b2, b3;
    { const bool ron = rv.x > 0.5f, zon = zv.x > 0.0f;
      const int sw = ron ? (zon ? i0 : 4) : -1;
      const int s2 = (ron && zon) ? i0 : 4;
      b0 = (unsigned)((sw + 1) << 4) | (unsigned)s2; }
    { const bool ron = rv.y > 0.5f, zon = zv.y > 0.0f;
      const int sw = ron ? (zon ? i1 : 4) : -1;
      const int s2 = (ron && zon) ? i1 : 4;
      b1 = (unsigned)((sw + 1) << 4) | (unsigned)s2; }
    { const bool ron = rv.z > 0.5f, zon = zv.z > 0.0f;
      const int sw = ron ? (zon ? i2 : 4) : -1;
      const int s2 = (ron && zon) ? i2 : 4;
      b2 = (unsigned)((sw + 1) << 4) | (unsigned)s2; }
    { const bool ron = rv.w > 0.5f, zon = zv.w > 0.0f;
      const int sw = ron ? (zon ? i3 : 4) : -1;
      const int s2 = (ron && zon) ? i3 : 4;
      b3 = (unsigned)((sw + 1) << 4) | (unsigned)s2; }

    sel[pix] = b0 | (b1 << 8) | (b2 << 16) | (b3 << 24);
}

// ---------------- Pass 2: linear plane writes ----------------
// grid = (S2, 36, B); block writes CHUNK4 contiguous float4 of plane (b,kc).
__global__ __launch_bounds__(256) void smap_write_kernel(
    const fvec4* __restrict__ x,
    const fvec4* __restrict__ y,
    const fvec4* __restrict__ z,
    const fvec4* __restrict__ r,
    const unsigned int* __restrict__ sel,
    fvec4* __restrict__ out)
{
    const int kc = blockIdx.y;            // [0,36)
    const int k  = kc >> 2;
    const int c  = kc & 3;
    const int bb = blockIdx.z;

    const fvec4* vp = (c == 0) ? x : (c == 1) ? y : (c == 2) ? z : r;
    vp += (size_t)bb * HW4;
    const unsigned int* sp = sel + (size_t)bb * HW4;
    fvec4* op = out + ((size_t)bb * 36 + kc) * HW4;

    const int base = blockIdx.x * CHUNK4;
    // hi nibble compares against k+1 (xyz), lo nibble against k (r)
    const unsigned int tgt = (c < 3) ? (unsigned)(k + 1) : (unsigned)k;
    const int shift = (c < 3) ? 4 : 0;    // block-uniform

#pragma unroll
    for (int it = 0; it < ITERS2; ++it) {
        const int f = base + it * BLK + threadIdx.x;
        const unsigned int s = sp[f];
        const fvec4 v = vp[f];            // regular: L3-resident re-reads
        fvec4 o;
        o.x = (((s >> (shift))      & 15u) == tgt) ? v.x : 0.0f;
        o.y = (((s >> (shift + 8))  & 15u) == tgt) ? v.y : 0.0f;
        o.z = (((s >> (shift + 16)) & 15u) == tgt) ? v.z : 0.0f;
        o.w = (((s >> (shift + 24)) & 15u) == tgt) ? v.w : 0.0f;
        nt_store4(op + f, o);
    }
}

extern "C" void kernel_launch(void* const* d_in, const int* in_sizes, int n_in,
                              void* d_out, int out_size, void* d_ws, size_t ws_size,
                              hipStream_t stream) {
    const fvec4* x  = (const fvec4*)d_in[0];
    const fvec4* y  = (const fvec4*)d_in[1];
    const fvec4* z  = (const fvec4*)d_in[2];
    const fvec4* r  = (const fvec4*)d_in[3];
    const fvec4* kq = (const fvec4*)d_in[4];
    fvec4* out = (fvec4*)d_out;
    unsigned int* sel = (unsigned int*)d_ws;   // B*HW4 uints = 1.23 MB

    smap_sel_kernel<<<dim3(GRIDX1, B), dim3(BLK), 0, stream>>>(z, r, kq, sel);
    smap_write_kernel<<<dim3(S2, 36, B), dim3(BLK), 0, stream>>>(x, y, z, r, sel, out);
}

// Round 6
// 226.456 us; speedup vs baseline: 1.0641x; 1.0641x over previous
//
#include <hip/hip_runtime.h>

// SMap3x3: per-pixel argmin over 9 key_query planes -> one-hot scatter of
// (x,y,z,r) into a [B,3,3,4,H,W] output. Pure streaming, HBM write-bound.
// Traffic floor: 64 MB read + 177 MB write = 241 MB ~= 38 us at fill rate.
//
// Case analysis of the reference (valid/bad mutually exclusive):
//   r<=0.5          : sw = -1 (no xz write), s2 = 4 (center)
//   r>0.5 && z>0    : sw = argmin,           s2 = argmin
//   r>0.5 && z<=0   : sw = 4,                s2 = 4
// out[b,k,c,hw] = c<3 ? ((k==sw) ? {x,y,z}[c] : 0) : ((k==s2) ? r : 0)
//
// Session findings (R1-R5):
//  - scalar vs array temporaries: neutral (no scratch demotion either way)
//  - NT loads/stores (bypass L2 alloc for read-once/write-once): -5.5 us
//  - two-pass (selector precompute + fill-like linear writes): +16 us
//    (regression == cost of the added pass) => single-pass is already at
//    the traffic floor; remaining bench time is harness reset work.
// This is the best-measured variant (R4, 224.8 us bench).

constexpr int H = 480;
constexpr int W = 640;
constexpr int HW = H * W;          // 307200
constexpr int HW4 = HW / 4;        // 76800 float4 per plane
constexpr int BLK = 256;
constexpr int GRIDX = HW4 / BLK;   // 300 (exact)

typedef __attribute__((ext_vector_type(4))) float fvec4;

__device__ __forceinline__ fvec4 nt_load4(const fvec4* p) {
    return __builtin_nontemporal_load(p);
}
__device__ __forceinline__ void nt_store4(fvec4* p, fvec4 v) {
    __builtin_nontemporal_store(v, p);
}

__global__ __launch_bounds__(256) void smap3x3_kernel(
    const fvec4* __restrict__ x,
    const fvec4* __restrict__ y,
    const fvec4* __restrict__ z,
    const fvec4* __restrict__ r,
    const fvec4* __restrict__ kq,
    fvec4* __restrict__ out)
{
    const int hw4 = blockIdx.x * BLK + threadIdx.x;  // [0, HW4)
    const int b   = blockIdx.y;                      // [0, 4)
    const size_t pix = (size_t)b * HW4 + hw4;

    const fvec4 xv = nt_load4(x + pix);
    const fvec4 yv = nt_load4(y + pix);
    const fvec4 zv = nt_load4(z + pix);
    const fvec4 rv = nt_load4(r + pix);

    // argmin over 9 planes, per component (first-occurrence tie-break: strict <)
    const fvec4* kqb = kq + (size_t)b * 9 * HW4 + hw4;
    fvec4 best = nt_load4(kqb);
    int i0 = 0, i1 = 0, i2 = 0, i3 = 0;
#pragma unroll
    for (int k = 1; k < 9; ++k) {
        const fvec4 kk = nt_load4(kqb + (size_t)k * HW4);
        if (kk.x < best.x) { best.x = kk.x; i0 = k; }
        if (kk.y < best.y) { best.y = kk.y; i1 = k; }
        if (kk.z < best.z) { best.z = kk.z; i2 = k; }
        if (kk.w < best.w) { best.w = kk.w; i3 = k; }
    }

    // per-component selectors
    int sw0, sw1, sw2, sw3;   // xyz plane selector (-1 = none)
    int s20, s21, s22, s23;   // r plane selector
    { const bool ron = rv.x > 0.5f, zon = zv.x > 0.0f;
      sw0 = ron ? (zon ? i0 : 4) : -1;  s20 = (ron && zon) ? i0 : 4; }
    { const bool ron = rv.y > 0.5f, zon = zv.y > 0.0f;
      sw1 = ron ? (zon ? i1 : 4) : -1;  s21 = (ron && zon) ? i1 : 4; }
    { const bool ron = rv.z > 0.5f, zon = zv.z > 0.0f;
      sw2 = ron ? (zon ? i2 : 4) : -1;  s22 = (ron && zon) ? i2 : 4; }
    { const bool ron = rv.w > 0.5f, zon = zv.w > 0.0f;
      sw3 = ron ? (zon ? i3 : 4) : -1;  s23 = (ron && zon) ? i3 : 4; }

    fvec4* outb = out + (size_t)b * 36 * HW4 + hw4;
#pragma unroll
    for (int k = 0; k < 9; ++k) {
        fvec4 ox, oy, oz, orr;
        const bool m0 = (k == sw0), m1 = (k == sw1), m2 = (k == sw2), m3 = (k == sw3);
        ox.x = m0 ? xv.x : 0.0f;  ox.y = m1 ? xv.y : 0.0f;
        ox.z = m2 ? xv.z : 0.0f;  ox.w = m3 ? xv.w : 0.0f;
        oy.x = m0 ? yv.x : 0.0f;  oy.y = m1 ? yv.y : 0.0f;
        oy.z = m2 ? yv.z : 0.0f;  oy.w = m3 ? yv.w : 0.0f;
        oz.x = m0 ? zv.x : 0.0f;  oz.y = m1 ? zv.y : 0.0f;
        oz.z = m2 ? zv.z : 0.0f;  oz.w = m3 ? zv.w : 0.0f;
        orr.x = (k == s20) ? rv.x : 0.0f;  orr.y = (k == s21) ? rv.y : 0.0f;
        orr.z = (k == s22) ? rv.z : 0.0f;  orr.w = (k == s23) ? rv.w : 0.0f;

        nt_store4(outb + (size_t)(4 * k + 0) * HW4, ox);
        nt_store4(outb + (size_t)(4 * k + 1) * HW4, oy);
        nt_store4(outb + (size_t)(4 * k + 2) * HW4, oz);
        nt_store4(outb + (size_t)(4 * k + 3) * HW4, orr);
    }
}

extern "C" void kernel_launch(void* const* d_in, const int* in_sizes, int n_in,
                              void* d_out, int out_size, void* d_ws, size_t ws_size,
                              hipStream_t stream) {
    const fvec4* x  = (const fvec4*)d_in[0];
    const fvec4* y  = (const fvec4*)d_in[1];
    const fvec4* z  = (const fvec4*)d_in[2];
    const fvec4* r  = (const fvec4*)d_in[3];
    const fvec4* kq = (const fvec4*)d_in[4];
    fvec4* out = (fvec4*)d_out;

    dim3 grid(GRIDX, 4);  // 300 x 4 blocks, exact cover
    smap3x3_kernel<<<grid, dim3(BLK), 0, stream>>>(x, y, z, r, kq, out);
}